// Round 15
// baseline (7863.539 us; speedup 1.0000x reference)
//
#include <hip/hip_runtime.h>

// QMogrifierStack: 2-layer mogrifier LSTM, B=64 S=512 IN=512 H=1024.
// R16 = R15 (decoupled layers, P1'=mod GEMM, Whh shadow under bar1, split-K
// wave pairs, WT stores + cached reads, per-XCD leader invalidate) with a
// FLATTENED 3-round barrier:
//  arrive: tid0 atomicFetchAdd on ONE monotone per-(layer,phase) counter;
//          the arriver seeing old==128*e-1 posts all[layer,phase]=e (no
//          master, no scatter-poll).
//  leaders: poll all-dword (+cross-layer dwords), buffer_inv sc1, post
//          per-XCD invflag.
//  followers: poll invflag only, buffer_inv sc0 (own L1).
// Leader = ticket 0 per (layer, HW_REG_XCC_ID) group - no mapping assumption.

typedef __attribute__((ext_vector_type(8))) short short8;
typedef __attribute__((ext_vector_type(4))) float f32x4;

constexpr int B_ = 64, S_ = 512, IN_ = 512, H_ = 1024;
constexpr int NBLK = 256, NTHR = 512;
constexpr int BH = B_ * H_;
constexpr int WP = 1032;              // LDS row pitch (shorts)
constexpr int D_ = 4;                 // h0 ring depth

__device__ __forceinline__ unsigned short f2bf(float f) {
  unsigned u = __builtin_bit_cast(unsigned, f);
  u += 0x7FFFu + ((u >> 16) & 1u);
  return (unsigned short)(u >> 16);
}
__device__ __forceinline__ float bf2f(unsigned short h) {
  unsigned u = ((unsigned)h) << 16;
  return __builtin_bit_cast(float, u);
}
__device__ __forceinline__ float sigm(float x) { return 1.f / (1.f + __expf(-x)); }
__device__ __forceinline__ float tanh_(float x) {
  float e = __expf(2.f * x);
  return 1.f - 2.f / (e + 1.f);
}

// Write-through stores (L2 stays clean; at coherence point after vmcnt(0)).
__device__ __forceinline__ void store_short_wt(unsigned short* p, unsigned short v) {
  unsigned w = v;
  asm volatile("global_store_short %0, %1, off sc0 sc1" :: "v"(p), "v"(w) : "memory");
}
__device__ __forceinline__ void store_float_wt(float* p, float v) {
  asm volatile("global_store_dword %0, %1, off sc0 sc1" :: "v"(p), "v"(v) : "memory");
}
__device__ __forceinline__ int aload(int* p) {
  return __hip_atomic_load(p, __ATOMIC_RELAXED, __HIP_MEMORY_SCOPE_AGENT);
}
__device__ __forceinline__ void astore(int* p, int v) {
  __hip_atomic_store(p, v, __ATOMIC_RELAXED, __HIP_MEMORY_SCOPE_AGENT);
}
__device__ __forceinline__ int aadd(int* p) {
  return __hip_atomic_fetch_add(p, 1, __ATOMIC_RELAXED, __HIP_MEMORY_SCOPE_AGENT);
}

__global__ __launch_bounds__(NTHR, 1) void qmog_kernel(
    const float* __restrict__ seq, const float* __restrict__ dseq,
    const float* __restrict__ lqseq,
    const float* __restrict__ modW0, const float* __restrict__ modb0,
    const float* __restrict__ Wih0, const float* __restrict__ Whh0,
    const float* __restrict__ bih0, const float* __restrict__ bhh0,
    const float* __restrict__ modW1, const float* __restrict__ modb1,
    const float* __restrict__ Wih1, const float* __restrict__ Whh1,
    const float* __restrict__ bih1, const float* __restrict__ bhh1,
    float* __restrict__ dout, int* __restrict__ flags,
    unsigned short* __restrict__ h0r, unsigned short* __restrict__ h1r,
    unsigned short* __restrict__ u0, unsigned short* __restrict__ u1) {
  __shared__ unsigned short Wih_s[32 * WP];   // 66048 B
  __shared__ unsigned short Whh_s[32 * WP];   // 66048 B
  __shared__ unsigned short modW_s[8 * WP];   // 16512 B
  __shared__ float red_s[4][8][64];           // 8192 B
  __shared__ float bias_s[32];
  __shared__ float wd_s[8], wl_s[8], mb_s[8];
  __shared__ int lead_s, xg_s;

  const int bid = blockIdx.x, tid = threadIdx.x;
  const int layer = bid >> 7;
  const int slice = bid & 127;
  const int wave = tid >> 6, lane = tid & 63;
  const int mt = wave & 3;            // M-tile (16 batch rows)
  const int kh = wave >> 2;           // K-half (0 or 1)
  const int Kin = layer ? H_ : IN_;   // 1024 / 512
  const int KU = Kin / 32;
  const int MCB = layer ? 8 : 4;      // m-cols per block
  const int hc0 = slice * 8;
  const int mc0 = slice * MCB;
  const float* modW = layer ? modW1 : modW0;
  const float* modb = layer ? modb1 : modb0;
  const float* Wih  = layer ? Wih1 : Wih0;
  const float* Whh  = layer ? Whh1 : Whh0;
  const float* bih  = layer ? bih1 : bih0;
  const float* bhh  = layer ? bhh1 : bhh0;
  unsigned short* ubuf = layer ? u1 : u0;

  // Barrier objects (all monotone epochs, memset 0 at launch):
  int* allA = &flags[896 + layer * 16];      // P1-arrive-complete dword
  int* allB = &flags[928 + layer * 16];      // P2-arrive-complete dword
  int* ctrA = &flags[960 + layer * 16];      // P1 arrive counter
  int* ctrB = &flags[992 + layer * 16];      // P2 arrive counter
  int* allB_L0 = &flags[928];                // cross-layer: L0 h0 published
  int* allA_L1 = &flags[896 + 16];           // cross-layer: L1 consumed h0

  // ---- XCD discovery + leader claim (ticket 0 per (layer,xcd) group) ----
  if (tid == 0) {
    unsigned xcc;
    asm volatile("s_getreg_b32 %0, hwreg(HW_REG_XCC_ID)" : "=s"(xcc));
    int g = layer * 8 + (int)(xcc & 7);
    xg_s = g;
    int tkt = __hip_atomic_fetch_add(&flags[1536 + g], 1, __ATOMIC_RELAXED,
                                     __HIP_MEMORY_SCOPE_AGENT);
    lead_s = (tkt == 0);
  }

  // ---- stage weight slices f32->bf16 into LDS ----
  // LDS row r -> gate row (r>>3)*H + hc0 + (r&7): [i0..7,f0..7,g0..7,o0..7]
  for (int idx = tid; idx < 32 * Kin; idx += NTHR) {
    int row = idx / Kin, k = idx - row * Kin;
    int grow = (row >> 3) * H_ + hc0 + (row & 7);
    Wih_s[row * WP + k] = f2bf(Wih[grow * Kin + k]);
  }
  for (int idx = tid; idx < 32 * H_; idx += NTHR) {
    int row = idx >> 10, k = idx & (H_ - 1);
    int grow = (row >> 3) * H_ + hc0 + (row & 7);
    Whh_s[row * WP + k] = f2bf(Whh[grow * H_ + k]);
  }
  for (int idx = tid; idx < MCB * H_; idx += NTHR) {
    int row = idx >> 10, k = idx & (H_ - 1);
    modW_s[row * WP + k] = f2bf(modW[(mc0 + row) * (H_ + 2) + k]);
  }
  if (tid < 32) {
    int grow = (tid >> 3) * H_ + hc0 + (tid & 7);
    bias_s[tid] = bih[grow] + bhh[grow];
  }
  if (tid < MCB) {
    wd_s[tid] = modW[(mc0 + tid) * (H_ + 2) + H_];
    wl_s[tid] = modW[(mc0 + tid) * (H_ + 2) + H_ + 1];
    mb_s[tid] = modb[mc0 + tid];
  }
  __syncthreads();
  const bool islead = (lead_s != 0);
  int* invA = &flags[1024 + xg_s * 16];   // top-of-step inv flag (per XCD)
  int* invB = &flags[1280 + xg_s * 16];   // bar1 inv flag (per XCD)

  float creg0 = 0.f, creg1 = 0.f;     // cell state (kh==0 waves only)
  const int c = lane & 15, kg = lane >> 4;
  const int cm = c & (MCB - 1);
  const bool epi = (!kh && c < MCB);
  const int ku2 = KU >> 1;            // 8 (L0) / 16 (L1) k-tiles per wave

  // Epilogue inputs, prefetched one step ahead (read-only globals).
  float dtv[4], lqv[4], xvv[4];
  if (epi) {
#pragma unroll
    for (int r = 0; r < 4; ++r) {
      int b_ = mt * 16 + kg * 4 + r;
      dtv[r] = dseq[b_ * S_];
      lqv[r] = lqseq[b_ * S_];
      if (!layer) xvv[r] = seq[(b_ * S_) * IN_ + mc0 + c];
    }
  }

  for (int st = 0; st < S_; ++st) {
    const int e = st + 1;

    // ---- top: leaders gate on allB(st-1) (+L1: L0's h0 ready), inv; ----
    // ---- followers gate on the per-XCD inv flag only.               ----
    if (tid == 0) {
      if (islead) {
        if (st > 0) while (aload(allB) < st) {}
        if (layer) while (aload(allB_L0) < e) {}   // h0_st at CP
        asm volatile("buffer_inv sc1\n\ts_waitcnt vmcnt(0)" ::: "memory");
        astore(invA, e);
      } else {
        while (aload(invA) < e) {}
        asm volatile("buffer_inv sc0\n\ts_waitcnt vmcnt(0)" ::: "memory");
      }
    }
    __syncthreads();

    // ---- h load (one L3 exposure); lives in regs through the Whh shadow ----
    const bool havh = (st > 0);
    short8 hv[16];
    if (havh) {
      const unsigned short* hrow =
          (layer ? h1r + ((st - 1) & 1) * BH : h0r + ((st - 1) % D_) * BH) +
          (mt * 16 + c) * H_ + kh * 512;
#pragma unroll
      for (int kk = 0; kk < 16; ++kk)
        hv[kk] = *(const short8*)(hrow + kk * 32 + kg * 8);
    }
    if (layer && epi) {                 // x = h0_st (fresh post-inv)
#pragma unroll
      for (int r = 0; r < 4; ++r) {
        int b_ = mt * 16 + kg * 4 + r;
        xvv[r] = bf2f(h0r[(st % D_) * BH + b_ * H_ + mc0 + c]);
      }
    }

    // ---- P1': mod GEMM only (2 chains), reduce m, u epilogue ----
    f32x4 mA = {0,0,0,0}, mB = {0,0,0,0};
    if (havh) {
      const unsigned short* wm = modW_s + cm * WP + kh * 512;
#pragma unroll
      for (int kk = 0; kk < 16; ++kk) {
        short8 bm = *(const short8*)(wm + kk * 32 + kg * 8);
        if (kk & 1)
          mB = __builtin_amdgcn_mfma_f32_16x16x32_bf16(hv[kk], bm, mB, 0, 0, 0);
        else
          mA = __builtin_amdgcn_mfma_f32_16x16x32_bf16(hv[kk], bm, mA, 0, 0, 0);
      }
    }
    if (kh) {
#pragma unroll
      for (int r = 0; r < 4; ++r) red_s[mt][r][lane] = mA[r] + mB[r];
    }
    __syncthreads();
    if (epi) {
      const float wd = wd_s[cm], wl = wl_s[cm], mb = mb_s[cm];
#pragma unroll
      for (int r = 0; r < 4; ++r) {
        int b_ = mt * 16 + kg * 4 + r;
        float mval = sigm(mA[r] + mB[r] + red_s[mt][r][lane] +
                          dtv[r] * wd + lqv[r] * wl + mb);
        store_short_wt(&ubuf[b_ * Kin + mc0 + c], f2bf(mval * xvv[r]));
      }
    }

    // ---- bar1 ARRIVE: drain u, one atomicAdd; last arriver posts allA ----
    asm volatile("s_waitcnt vmcnt(0)" ::: "memory");
    __syncthreads();
    if (tid == 0) {
      int old = aadd(ctrA);
      if (old == 128 * e - 1) astore(allA, e);
    }

    // ---- SHADOW: Whh GEMM (hv regs + LDS only; hides bar1 latency) ----
    f32x4 p0 = {0,0,0,0}, p1 = {0,0,0,0};
    if (havh) {
      const unsigned short* w0b = Whh_s + c * WP + kh * 512;
      const unsigned short* w1b = Whh_s + (16 + c) * WP + kh * 512;
#pragma unroll
      for (int kk = 0; kk < 16; ++kk) {
        short8 w0 = *(const short8*)(w0b + kk * 32 + kg * 8);
        short8 w1 = *(const short8*)(w1b + kk * 32 + kg * 8);
        p0 = __builtin_amdgcn_mfma_f32_16x16x32_bf16(hv[kk], w0, p0, 0, 0, 0);
        p1 = __builtin_amdgcn_mfma_f32_16x16x32_bf16(hv[kk], w1, p1, 0, 0, 0);
      }
    }

    // ---- bar1 WAIT: leaders gate on allA (+L0 ring back-pressure), inv ----
    if (tid == 0) {
      if (islead) {
        while (aload(allA) < e) {}
        if (!layer && st >= D_) {   // don't overwrite h0 slot until L1 read it
          while (aload(allA_L1) < st - D_ + 1) {}
        }
        asm volatile("buffer_inv sc1\n\ts_waitcnt vmcnt(0)" ::: "memory");
        astore(invB, e);
      } else {
        while (aload(invB) < e) {}
        asm volatile("buffer_inv sc0\n\ts_waitcnt vmcnt(0)" ::: "memory");
      }
    }
    __syncthreads();

    // ---- P2': u@Wih^T split-K; merged (p+g) reduce; cell ----
    {
      const unsigned short* urow = ubuf + (mt * 16 + c) * Kin + kh * (ku2 * 32);
      short8 uv[16];
#pragma unroll
      for (int kk = 0; kk < 16; ++kk)
        if (kk < ku2) uv[kk] = *(const short8*)(urow + kk * 32 + kg * 8);
      f32x4 g0 = {0,0,0,0}, g1 = {0,0,0,0};
      const unsigned short* v0b = Wih_s + c * WP + kh * (ku2 * 32);
      const unsigned short* v1b = Wih_s + (16 + c) * WP + kh * (ku2 * 32);
#pragma unroll
      for (int kk = 0; kk < 16; ++kk) {
        if (kk < ku2) {
          short8 v0 = *(const short8*)(v0b + kk * 32 + kg * 8);
          short8 v1 = *(const short8*)(v1b + kk * 32 + kg * 8);
          g0 = __builtin_amdgcn_mfma_f32_16x16x32_bf16(uv[kk], v0, g0, 0, 0, 0);
          g1 = __builtin_amdgcn_mfma_f32_16x16x32_bf16(uv[kk], v1, g1, 0, 0, 0);
        }
      }
      if (kh) {
#pragma unroll
        for (int r = 0; r < 4; ++r) {
          red_s[mt][r][lane] = g0[r] + p0[r];
          red_s[mt][4 + r][lane] = g1[r] + p1[r];
        }
      }
      __syncthreads();               // block-uniform branch: legal
      if (!kh) {
        const float bia0 = bias_s[c], bia1 = bias_s[16 + c];
        f32x4 s0, s1;
#pragma unroll
        for (int r = 0; r < 4; ++r) {
          g0[r] += p0[r] + red_s[mt][r][lane] + bia0;
          g1[r] += p1[r] + red_s[mt][4 + r][lane] + bia1;
        }
#pragma unroll
        for (int r = 0; r < 4; ++r) {
          s0[r] = __shfl_xor(g0[r], 8);
          s1[r] = __shfl_xor(g1[r], 8);
        }
        // Lane c<8 holds i (tile0) / g (tile1); c>=8 holds f / o.
        const bool low = c < 8;
        const int hc = hc0 + (c & 7);
        const int rbase = low ? 0 : 2;
        unsigned short* hw = layer ? h1r + (st & 1) * BH : h0r + (st % D_) * BH;
#pragma unroll
        for (int j = 0; j < 2; ++j) {
          const int rr = rbase + j;
          float iv = low ? g0[rr] : s0[rr];
          float fv = low ? s0[rr] : g0[rr];
          float gv = low ? g1[rr] : s1[rr];
          float ov = low ? s1[rr] : g1[rr];
          float cold = j ? creg1 : creg0;
          float cn = sigm(fv) * cold + sigm(iv) * tanh_(gv);
          float hn = sigm(ov) * tanh_(cn);
          if (j) creg1 = cn; else creg0 = cn;
          int b_ = mt * 16 + kg * 4 + rr;
          store_short_wt(&hw[b_ * H_ + hc], f2bf(hn));
          if (layer) {
            store_float_wt(&dout[(b_ * S_ + st) * H_ + hc], hn);
            if (st == S_ - 1) store_float_wt(&dout[B_ * S_ * H_ + b_ * H_ + hc], hn);
          }
        }
      }
    }

    // ---- bar2 ARRIVE: drain h, one atomicAdd; last arriver posts allB ----
    asm volatile("s_waitcnt vmcnt(0)" ::: "memory");
    __syncthreads();
    if (tid == 0) {
      int old = aadd(ctrB);
      if (old == 128 * e - 1) astore(allB, e);
    }

    // ---- under-barrier prefetch: next step's read-only epilogue inputs ----
    const int t2 = st + 1;
    if (t2 < S_ && epi) {
#pragma unroll
      for (int r = 0; r < 4; ++r) {
        int b_ = mt * 16 + kg * 4 + r;
        dtv[r] = dseq[b_ * S_ + t2];
        lqv[r] = lqseq[b_ * S_ + t2];
        if (!layer) xvv[r] = seq[(b_ * S_ + t2) * IN_ + mc0 + c];
      }
    }
  }
}

extern "C" void kernel_launch(void* const* d_in, const int* in_sizes, int n_in,
                              void* d_out, int out_size, void* d_ws,
                              size_t ws_size, hipStream_t stream) {
  char* w = (char*)d_ws;
  int* flags = (int*)w;                                        // <8 KB used
  unsigned short* h0r = (unsigned short*)(w + 16384);          // 4 x 128 KB ring
  unsigned short* h1r = (unsigned short*)(w + 16384 + 524288); // 2 x 128 KB
  unsigned short* u0 = (unsigned short*)(w + 16384 + 524288 + 262144);          // 64 KB
  unsigned short* u1 = (unsigned short*)(w + 16384 + 524288 + 262144 + 65536);  // 128 KB

  hipMemsetAsync(flags, 0, 16384, stream);   // fresh epochs/counters each launch

  qmog_kernel<<<NBLK, NTHR, 0, stream>>>(
      (const float*)d_in[0], (const float*)d_in[1], (const float*)d_in[2],
      (const float*)d_in[3], (const float*)d_in[4], (const float*)d_in[5],
      (const float*)d_in[6], (const float*)d_in[7], (const float*)d_in[8],
      (const float*)d_in[9], (const float*)d_in[10], (const float*)d_in[11],
      (const float*)d_in[12], (const float*)d_in[13], (const float*)d_in[14],
      (float*)d_out, flags, h0r, h1r, u0, u1);
}

// Round 16
// 7543.099 us; speedup vs baseline: 1.0425x; 1.0425x over previous
//
#include <hip/hip_runtime.h>

// QMogrifierStack: 2-layer mogrifier LSTM, B=64 S=512 IN=512 H=1024.
// R17 = R15 (decoupled layers, P1'=mod GEMM, Whh shadow under bar1, split-K
// wave pairs, WT stores + cached reads, per-XCD leader invalidate) with
// DIRECT LEADER DETECT: no master block, no go slots. Each (layer,XCD)
// leader's wave 0 scatter-polls the 128 per-block arrive flags itself
// (parallel detect, s_sleep backoff), then buffer_inv sc1 + posts the
// per-XCD inv flag; followers poll ONLY that flag + buffer_inv sc0.
// Removes one CP round-trip (go hop) per barrier. Cross-layer coupling via
// two monotone dwords (h0done / l1p1done) checked by leaders pre-inv.
// R16 lesson kept: arrive = per-block flag store (never a shared counter).

typedef __attribute__((ext_vector_type(8))) short short8;
typedef __attribute__((ext_vector_type(4))) float f32x4;

constexpr int B_ = 64, S_ = 512, IN_ = 512, H_ = 1024;
constexpr int NBLK = 256, NTHR = 512;
constexpr int BH = B_ * H_;
constexpr int WP = 1032;              // LDS row pitch (shorts)
constexpr int D_ = 4;                 // h0 ring depth

__device__ __forceinline__ unsigned short f2bf(float f) {
  unsigned u = __builtin_bit_cast(unsigned, f);
  u += 0x7FFFu + ((u >> 16) & 1u);
  return (unsigned short)(u >> 16);
}
__device__ __forceinline__ float bf2f(unsigned short h) {
  unsigned u = ((unsigned)h) << 16;
  return __builtin_bit_cast(float, u);
}
__device__ __forceinline__ float sigm(float x) { return 1.f / (1.f + __expf(-x)); }
__device__ __forceinline__ float tanh_(float x) {
  float e = __expf(2.f * x);
  return 1.f - 2.f / (e + 1.f);
}

// Write-through stores (L2 stays clean; at coherence point after vmcnt(0)).
__device__ __forceinline__ void store_short_wt(unsigned short* p, unsigned short v) {
  unsigned w = v;
  asm volatile("global_store_short %0, %1, off sc0 sc1" :: "v"(p), "v"(w) : "memory");
}
__device__ __forceinline__ void store_float_wt(float* p, float v) {
  asm volatile("global_store_dword %0, %1, off sc0 sc1" :: "v"(p), "v"(v) : "memory");
}
__device__ __forceinline__ int aload(int* p) {
  return __hip_atomic_load(p, __ATOMIC_RELAXED, __HIP_MEMORY_SCOPE_AGENT);
}
__device__ __forceinline__ void astore(int* p, int v) {
  __hip_atomic_store(p, v, __ATOMIC_RELAXED, __HIP_MEMORY_SCOPE_AGENT);
}

// Leader parallel detect: 64 lanes poll 2 flags each until all >= target.
__device__ __forceinline__ void leader_detect(int* arr, int target, int lane) {
  for (;;) {
    bool ok = (aload(&arr[lane]) >= target) & (aload(&arr[lane + 64]) >= target);
    if (__all(ok)) break;
    __builtin_amdgcn_s_sleep(1);
  }
}

__global__ __launch_bounds__(NTHR, 1) void qmog_kernel(
    const float* __restrict__ seq, const float* __restrict__ dseq,
    const float* __restrict__ lqseq,
    const float* __restrict__ modW0, const float* __restrict__ modb0,
    const float* __restrict__ Wih0, const float* __restrict__ Whh0,
    const float* __restrict__ bih0, const float* __restrict__ bhh0,
    const float* __restrict__ modW1, const float* __restrict__ modb1,
    const float* __restrict__ Wih1, const float* __restrict__ Whh1,
    const float* __restrict__ bih1, const float* __restrict__ bhh1,
    float* __restrict__ dout, int* __restrict__ flags,
    unsigned short* __restrict__ h0r, unsigned short* __restrict__ h1r,
    unsigned short* __restrict__ u0, unsigned short* __restrict__ u1) {
  __shared__ unsigned short Wih_s[32 * WP];   // 66048 B
  __shared__ unsigned short Whh_s[32 * WP];   // 66048 B
  __shared__ unsigned short modW_s[8 * WP];   // 16512 B
  __shared__ float red_s[4][8][64];           // 8192 B
  __shared__ float bias_s[32];
  __shared__ float wd_s[8], wl_s[8], mb_s[8];
  __shared__ int lead_s, xg_s;

  const int bid = blockIdx.x, tid = threadIdx.x;
  const int layer = bid >> 7;
  const int slice = bid & 127;
  const int wave = tid >> 6, lane = tid & 63;
  const int mt = wave & 3;            // M-tile (16 batch rows)
  const int kh = wave >> 2;           // K-half (0 or 1)
  const int Kin = layer ? H_ : IN_;   // 1024 / 512
  const int KU = Kin / 32;
  const int MCB = layer ? 8 : 4;      // m-cols per block
  const int hc0 = slice * 8;
  const int mc0 = slice * MCB;
  const float* modW = layer ? modW1 : modW0;
  const float* modb = layer ? modb1 : modb0;
  const float* Wih  = layer ? Wih1 : Wih0;
  const float* Whh  = layer ? Whh1 : Whh0;
  const float* bih  = layer ? bih1 : bih0;
  const float* bhh  = layer ? bhh1 : bhh0;
  unsigned short* ubuf = layer ? u1 : u0;

  // flags layout (ints): [0..127] arrL0, [128..255] arrL1 (monotone epochs),
  // [768] h0done, [800] l1p1done, [1024+16x] invA, [1280+16x] invB,
  // [1536+g] leader tickets.
  int* arrL = flags + layer * 128;
  int* h0done = &flags[768];
  int* l1p1done = &flags[800];

  // ---- XCD discovery + leader claim (ticket 0 per (layer,xcd) group) ----
  if (tid == 0) {
    unsigned xcc;
    asm volatile("s_getreg_b32 %0, hwreg(HW_REG_XCC_ID)" : "=s"(xcc));
    int g = layer * 8 + (int)(xcc & 7);
    xg_s = g;
    int tkt = __hip_atomic_fetch_add(&flags[1536 + g], 1, __ATOMIC_RELAXED,
                                     __HIP_MEMORY_SCOPE_AGENT);
    lead_s = (tkt == 0);
  }

  // ---- stage weight slices f32->bf16 into LDS ----
  // LDS row r -> gate row (r>>3)*H + hc0 + (r&7): [i0..7,f0..7,g0..7,o0..7]
  for (int idx = tid; idx < 32 * Kin; idx += NTHR) {
    int row = idx / Kin, k = idx - row * Kin;
    int grow = (row >> 3) * H_ + hc0 + (row & 7);
    Wih_s[row * WP + k] = f2bf(Wih[grow * Kin + k]);
  }
  for (int idx = tid; idx < 32 * H_; idx += NTHR) {
    int row = idx >> 10, k = idx & (H_ - 1);
    int grow = (row >> 3) * H_ + hc0 + (row & 7);
    Whh_s[row * WP + k] = f2bf(Whh[grow * H_ + k]);
  }
  for (int idx = tid; idx < MCB * H_; idx += NTHR) {
    int row = idx >> 10, k = idx & (H_ - 1);
    modW_s[row * WP + k] = f2bf(modW[(mc0 + row) * (H_ + 2) + k]);
  }
  if (tid < 32) {
    int grow = (tid >> 3) * H_ + hc0 + (tid & 7);
    bias_s[tid] = bih[grow] + bhh[grow];
  }
  if (tid < MCB) {
    wd_s[tid] = modW[(mc0 + tid) * (H_ + 2) + H_];
    wl_s[tid] = modW[(mc0 + tid) * (H_ + 2) + H_ + 1];
    mb_s[tid] = modb[mc0 + tid];
  }
  __syncthreads();
  const bool islead = (lead_s != 0);
  int* invA = &flags[1024 + xg_s * 16];   // top-of-step inv flag (per XCD)
  int* invB = &flags[1280 + xg_s * 16];   // bar1 inv flag (per XCD)

  float creg0 = 0.f, creg1 = 0.f;     // cell state (kh==0 waves only)
  const int c = lane & 15, kg = lane >> 4;
  const int cm = c & (MCB - 1);
  const bool epi = (!kh && c < MCB);
  const int ku2 = KU >> 1;            // 8 (L0) / 16 (L1) k-tiles per wave

  // Epilogue inputs, prefetched one step ahead (read-only globals).
  float dtv[4], lqv[4], xvv[4];
  if (epi) {
#pragma unroll
    for (int r = 0; r < 4; ++r) {
      int b_ = mt * 16 + kg * 4 + r;
      dtv[r] = dseq[b_ * S_];
      lqv[r] = lqseq[b_ * S_];
      if (!layer) xvv[r] = seq[(b_ * S_) * IN_ + mc0 + c];
    }
  }

  for (int st = 0; st < S_; ++st) {
    const int e = st + 1;

    // ---- top sync: leaders detect bar2(st-1) directly, inv, post invA ----
    if (islead) {
      if (wave == 0) {
        if (st > 0) leader_detect(arrL, 2 * st, lane);
        if (lane == 0) {
          if (!layer) astore(h0done, st);          // h0 slots < st complete
          if (layer) while (aload(h0done) < e) {}  // h0 slot st at CP
          asm volatile("buffer_inv sc1\n\ts_waitcnt vmcnt(0)" ::: "memory");
          astore(invA, e);
        }
      }
    } else if (tid == 0) {
      while (aload(invA) < e) {}
      asm volatile("buffer_inv sc0\n\ts_waitcnt vmcnt(0)" ::: "memory");
    }
    __syncthreads();

    // ---- h load (one L3 exposure); lives in regs through the Whh shadow ----
    const bool havh = (st > 0);
    short8 hv[16];
    if (havh) {
      const unsigned short* hrow =
          (layer ? h1r + ((st - 1) & 1) * BH : h0r + ((st - 1) % D_) * BH) +
          (mt * 16 + c) * H_ + kh * 512;
#pragma unroll
      for (int kk = 0; kk < 16; ++kk)
        hv[kk] = *(const short8*)(hrow + kk * 32 + kg * 8);
    }
    if (layer && epi) {                 // x = h0_st (fresh post-inv)
#pragma unroll
      for (int r = 0; r < 4; ++r) {
        int b_ = mt * 16 + kg * 4 + r;
        xvv[r] = bf2f(h0r[(st % D_) * BH + b_ * H_ + mc0 + c]);
      }
    }

    // ---- P1': mod GEMM only (2 chains), reduce m, u epilogue ----
    f32x4 mA = {0,0,0,0}, mB = {0,0,0,0};
    if (havh) {
      const unsigned short* wm = modW_s + cm * WP + kh * 512;
#pragma unroll
      for (int kk = 0; kk < 16; ++kk) {
        short8 bm = *(const short8*)(wm + kk * 32 + kg * 8);
        if (kk & 1)
          mB = __builtin_amdgcn_mfma_f32_16x16x32_bf16(hv[kk], bm, mB, 0, 0, 0);
        else
          mA = __builtin_amdgcn_mfma_f32_16x16x32_bf16(hv[kk], bm, mA, 0, 0, 0);
      }
    }
    if (kh) {
#pragma unroll
      for (int r = 0; r < 4; ++r) red_s[mt][r][lane] = mA[r] + mB[r];
    }
    __syncthreads();
    if (epi) {
      const float wd = wd_s[cm], wl = wl_s[cm], mb = mb_s[cm];
#pragma unroll
      for (int r = 0; r < 4; ++r) {
        int b_ = mt * 16 + kg * 4 + r;
        float mval = sigm(mA[r] + mB[r] + red_s[mt][r][lane] +
                          dtv[r] * wd + lqv[r] * wl + mb);
        store_short_wt(&ubuf[b_ * Kin + mc0 + c], f2bf(mval * xvv[r]));
      }
    }

    // ---- bar1 ARRIVE (early; u drained first) ----
    asm volatile("s_waitcnt vmcnt(0)" ::: "memory");
    __syncthreads();
    if (tid == 0) astore(&arrL[slice], 2 * st + 1);

    // ---- SHADOW: Whh GEMM (hv regs + LDS only; hides bar1 latency) ----
    f32x4 p0 = {0,0,0,0}, p1 = {0,0,0,0};
    if (havh) {
      const unsigned short* w0b = Whh_s + c * WP + kh * 512;
      const unsigned short* w1b = Whh_s + (16 + c) * WP + kh * 512;
#pragma unroll
      for (int kk = 0; kk < 16; ++kk) {
        short8 w0 = *(const short8*)(w0b + kk * 32 + kg * 8);
        short8 w1 = *(const short8*)(w1b + kk * 32 + kg * 8);
        p0 = __builtin_amdgcn_mfma_f32_16x16x32_bf16(hv[kk], w0, p0, 0, 0, 0);
        p1 = __builtin_amdgcn_mfma_f32_16x16x32_bf16(hv[kk], w1, p1, 0, 0, 0);
      }
    }

    // ---- bar1 sync: leaders detect directly (+L0 ring back-pressure) ----
    if (islead) {
      if (wave == 0) {
        leader_detect(arrL, 2 * st + 1, lane);
        if (lane == 0) {
          if (layer) astore(l1p1done, e);          // L1 P1(st) reads complete
          if (!layer && st >= D_) {                // h0 slot reuse gate
            while (aload(l1p1done) < st - D_ + 1) {}
          }
          asm volatile("buffer_inv sc1\n\ts_waitcnt vmcnt(0)" ::: "memory");
          astore(invB, e);
        }
      }
    } else if (tid == 0) {
      while (aload(invB) < e) {}
      asm volatile("buffer_inv sc0\n\ts_waitcnt vmcnt(0)" ::: "memory");
    }
    __syncthreads();

    // ---- P2': u@Wih^T split-K; merged (p+g) reduce; cell ----
    {
      const unsigned short* urow = ubuf + (mt * 16 + c) * Kin + kh * (ku2 * 32);
      short8 uv[16];
#pragma unroll
      for (int kk = 0; kk < 16; ++kk)
        if (kk < ku2) uv[kk] = *(const short8*)(urow + kk * 32 + kg * 8);
      f32x4 g0 = {0,0,0,0}, g1 = {0,0,0,0};
      const unsigned short* v0b = Wih_s + c * WP + kh * (ku2 * 32);
      const unsigned short* v1b = Wih_s + (16 + c) * WP + kh * (ku2 * 32);
#pragma unroll
      for (int kk = 0; kk < 16; ++kk) {
        if (kk < ku2) {
          short8 v0 = *(const short8*)(v0b + kk * 32 + kg * 8);
          short8 v1 = *(const short8*)(v1b + kk * 32 + kg * 8);
          g0 = __builtin_amdgcn_mfma_f32_16x16x32_bf16(uv[kk], v0, g0, 0, 0, 0);
          g1 = __builtin_amdgcn_mfma_f32_16x16x32_bf16(uv[kk], v1, g1, 0, 0, 0);
        }
      }
      if (kh) {
#pragma unroll
        for (int r = 0; r < 4; ++r) {
          red_s[mt][r][lane] = g0[r] + p0[r];
          red_s[mt][4 + r][lane] = g1[r] + p1[r];
        }
      }
      __syncthreads();               // block-uniform branch: legal
      if (!kh) {
        const float bia0 = bias_s[c], bia1 = bias_s[16 + c];
        f32x4 s0, s1;
#pragma unroll
        for (int r = 0; r < 4; ++r) {
          g0[r] += p0[r] + red_s[mt][r][lane] + bia0;
          g1[r] += p1[r] + red_s[mt][4 + r][lane] + bia1;
        }
#pragma unroll
        for (int r = 0; r < 4; ++r) {
          s0[r] = __shfl_xor(g0[r], 8);
          s1[r] = __shfl_xor(g1[r], 8);
        }
        // Lane c<8 holds i (tile0) / g (tile1); c>=8 holds f / o.
        const bool low = c < 8;
        const int hc = hc0 + (c & 7);
        const int rbase = low ? 0 : 2;
        unsigned short* hw = layer ? h1r + (st & 1) * BH : h0r + (st % D_) * BH;
#pragma unroll
        for (int j = 0; j < 2; ++j) {
          const int rr = rbase + j;
          float iv = low ? g0[rr] : s0[rr];
          float fv = low ? s0[rr] : g0[rr];
          float gv = low ? g1[rr] : s1[rr];
          float ov = low ? s1[rr] : g1[rr];
          float cold = j ? creg1 : creg0;
          float cn = sigm(fv) * cold + sigm(iv) * tanh_(gv);
          float hn = sigm(ov) * tanh_(cn);
          if (j) creg1 = cn; else creg0 = cn;
          int b_ = mt * 16 + kg * 4 + rr;
          store_short_wt(&hw[b_ * H_ + hc], f2bf(hn));
          if (layer) {
            store_float_wt(&dout[(b_ * S_ + st) * H_ + hc], hn);
            if (st == S_ - 1) store_float_wt(&dout[B_ * S_ * H_ + b_ * H_ + hc], hn);
          }
        }
      }
    }

    // ---- bar2 ARRIVE: drain h, post arrive flag ----
    asm volatile("s_waitcnt vmcnt(0)" ::: "memory");
    __syncthreads();
    if (tid == 0) astore(&arrL[slice], 2 * st + 2);

    // ---- under-barrier prefetch: next step's read-only epilogue inputs ----
    const int t2 = st + 1;
    if (t2 < S_ && epi) {
#pragma unroll
      for (int r = 0; r < 4; ++r) {
        int b_ = mt * 16 + kg * 4 + r;
        dtv[r] = dseq[b_ * S_ + t2];
        lqv[r] = lqseq[b_ * S_ + t2];
        if (!layer) xvv[r] = seq[(b_ * S_ + t2) * IN_ + mc0 + c];
      }
    }
  }

  // ---- final: L0 leaders confirm bar2(S-1) so L1's last h0done poll ends ----
  if (!layer && islead && wave == 0) {
    leader_detect(arrL, 2 * S_, lane);
    if (lane == 0) astore(h0done, S_);
  }
}

extern "C" void kernel_launch(void* const* d_in, const int* in_sizes, int n_in,
                              void* d_out, int out_size, void* d_ws,
                              size_t ws_size, hipStream_t stream) {
  char* w = (char*)d_ws;
  int* flags = (int*)w;                                        // <8 KB used
  unsigned short* h0r = (unsigned short*)(w + 16384);          // 4 x 128 KB ring
  unsigned short* h1r = (unsigned short*)(w + 16384 + 524288); // 2 x 128 KB
  unsigned short* u0 = (unsigned short*)(w + 16384 + 524288 + 262144);          // 64 KB
  unsigned short* u1 = (unsigned short*)(w + 16384 + 524288 + 262144 + 65536);  // 128 KB

  hipMemsetAsync(flags, 0, 16384, stream);   // fresh epochs/tickets each launch

  qmog_kernel<<<NBLK, NTHR, 0, stream>>>(
      (const float*)d_in[0], (const float*)d_in[1], (const float*)d_in[2],
      (const float*)d_in[3], (const float*)d_in[4], (const float*)d_in[5],
      (const float*)d_in[6], (const float*)d_in[7], (const float*)d_in[8],
      (const float*)d_in[9], (const float*)d_in[10], (const float*)d_in[11],
      (const float*)d_in[12], (const float*)d_in[13], (const float*)d_in[14],
      (float*)d_out, flags, h0r, h1r, u0, u1);
}

// Round 17
// 7418.211 us; speedup vs baseline: 1.0600x; 1.0168x over previous
//
#include <hip/hip_runtime.h>

// QMogrifierStack: 2-layer mogrifier LSTM, B=64 S=512 IN=512 H=1024.
// R18 = R17 (decoupled layers, direct leader detect, per-XCD leader inv,
// split-K wave pairs, WT stores + cached reads) with:
//  - NO top-of-step invalidate: invB (bar1) alone guarantees freshness for
//    h0/h1/u (traced: every stale-copy window has an invB between last
//    old-value read and the new write; no reads occur in between). Top sync
//    is now pure detect + go flag.
//  - SPLIT Whh shadow: 8 k-tiles before the u-store drain (hides WT ack),
//    8 k-tiles after bar1-arrive (hides detect), p0/p1 carried in regs.

typedef __attribute__((ext_vector_type(8))) short short8;
typedef __attribute__((ext_vector_type(4))) float f32x4;

constexpr int B_ = 64, S_ = 512, IN_ = 512, H_ = 1024;
constexpr int NBLK = 256, NTHR = 512;
constexpr int BH = B_ * H_;
constexpr int WP = 1032;              // LDS row pitch (shorts)
constexpr int D_ = 4;                 // h0 ring depth

__device__ __forceinline__ unsigned short f2bf(float f) {
  unsigned u = __builtin_bit_cast(unsigned, f);
  u += 0x7FFFu + ((u >> 16) & 1u);
  return (unsigned short)(u >> 16);
}
__device__ __forceinline__ float bf2f(unsigned short h) {
  unsigned u = ((unsigned)h) << 16;
  return __builtin_bit_cast(float, u);
}
__device__ __forceinline__ float sigm(float x) { return 1.f / (1.f + __expf(-x)); }
__device__ __forceinline__ float tanh_(float x) {
  float e = __expf(2.f * x);
  return 1.f - 2.f / (e + 1.f);
}

// Write-through stores (L2 stays clean; at coherence point after vmcnt(0)).
__device__ __forceinline__ void store_short_wt(unsigned short* p, unsigned short v) {
  unsigned w = v;
  asm volatile("global_store_short %0, %1, off sc0 sc1" :: "v"(p), "v"(w) : "memory");
}
__device__ __forceinline__ void store_float_wt(float* p, float v) {
  asm volatile("global_store_dword %0, %1, off sc0 sc1" :: "v"(p), "v"(v) : "memory");
}
__device__ __forceinline__ int aload(int* p) {
  return __hip_atomic_load(p, __ATOMIC_RELAXED, __HIP_MEMORY_SCOPE_AGENT);
}
__device__ __forceinline__ void astore(int* p, int v) {
  __hip_atomic_store(p, v, __ATOMIC_RELAXED, __HIP_MEMORY_SCOPE_AGENT);
}

// Leader parallel detect: 64 lanes poll 2 flags each until all >= target.
__device__ __forceinline__ void leader_detect(int* arr, int target, int lane) {
  for (;;) {
    bool ok = (aload(&arr[lane]) >= target) & (aload(&arr[lane + 64]) >= target);
    if (__all(ok)) break;
    __builtin_amdgcn_s_sleep(1);
  }
}

__global__ __launch_bounds__(NTHR, 1) void qmog_kernel(
    const float* __restrict__ seq, const float* __restrict__ dseq,
    const float* __restrict__ lqseq,
    const float* __restrict__ modW0, const float* __restrict__ modb0,
    const float* __restrict__ Wih0, const float* __restrict__ Whh0,
    const float* __restrict__ bih0, const float* __restrict__ bhh0,
    const float* __restrict__ modW1, const float* __restrict__ modb1,
    const float* __restrict__ Wih1, const float* __restrict__ Whh1,
    const float* __restrict__ bih1, const float* __restrict__ bhh1,
    float* __restrict__ dout, int* __restrict__ flags,
    unsigned short* __restrict__ h0r, unsigned short* __restrict__ h1r,
    unsigned short* __restrict__ u0, unsigned short* __restrict__ u1) {
  __shared__ unsigned short Wih_s[32 * WP];   // 66048 B
  __shared__ unsigned short Whh_s[32 * WP];   // 66048 B
  __shared__ unsigned short modW_s[8 * WP];   // 16512 B
  __shared__ float red_s[4][8][64];           // 8192 B
  __shared__ float bias_s[32];
  __shared__ float wd_s[8], wl_s[8], mb_s[8];
  __shared__ int lead_s, xg_s;

  const int bid = blockIdx.x, tid = threadIdx.x;
  const int layer = bid >> 7;
  const int slice = bid & 127;
  const int wave = tid >> 6, lane = tid & 63;
  const int mt = wave & 3;            // M-tile (16 batch rows)
  const int kh = wave >> 2;           // K-half (0 or 1)
  const int Kin = layer ? H_ : IN_;   // 1024 / 512
  const int KU = Kin / 32;
  const int MCB = layer ? 8 : 4;      // m-cols per block
  const int hc0 = slice * 8;
  const int mc0 = slice * MCB;
  const float* modW = layer ? modW1 : modW0;
  const float* modb = layer ? modb1 : modb0;
  const float* Wih  = layer ? Wih1 : Wih0;
  const float* Whh  = layer ? Whh1 : Whh0;
  const float* bih  = layer ? bih1 : bih0;
  const float* bhh  = layer ? bhh1 : bhh0;
  unsigned short* ubuf = layer ? u1 : u0;

  // flags layout (ints): [0..127] arrL0, [128..255] arrL1 (monotone epochs),
  // [768] h0done, [800] l1p1done, [1024+16x] goA, [1280+16x] invB,
  // [1536+g] leader tickets.
  int* arrL = flags + layer * 128;
  int* h0done = &flags[768];
  int* l1p1done = &flags[800];

  // ---- XCD discovery + leader claim (ticket 0 per (layer,xcd) group) ----
  if (tid == 0) {
    unsigned xcc;
    asm volatile("s_getreg_b32 %0, hwreg(HW_REG_XCC_ID)" : "=s"(xcc));
    int g = layer * 8 + (int)(xcc & 7);
    xg_s = g;
    int tkt = __hip_atomic_fetch_add(&flags[1536 + g], 1, __ATOMIC_RELAXED,
                                     __HIP_MEMORY_SCOPE_AGENT);
    lead_s = (tkt == 0);
  }

  // ---- stage weight slices f32->bf16 into LDS ----
  // LDS row r -> gate row (r>>3)*H + hc0 + (r&7): [i0..7,f0..7,g0..7,o0..7]
  for (int idx = tid; idx < 32 * Kin; idx += NTHR) {
    int row = idx / Kin, k = idx - row * Kin;
    int grow = (row >> 3) * H_ + hc0 + (row & 7);
    Wih_s[row * WP + k] = f2bf(Wih[grow * Kin + k]);
  }
  for (int idx = tid; idx < 32 * H_; idx += NTHR) {
    int row = idx >> 10, k = idx & (H_ - 1);
    int grow = (row >> 3) * H_ + hc0 + (row & 7);
    Whh_s[row * WP + k] = f2bf(Whh[grow * H_ + k]);
  }
  for (int idx = tid; idx < MCB * H_; idx += NTHR) {
    int row = idx >> 10, k = idx & (H_ - 1);
    modW_s[row * WP + k] = f2bf(modW[(mc0 + row) * (H_ + 2) + k]);
  }
  if (tid < 32) {
    int grow = (tid >> 3) * H_ + hc0 + (tid & 7);
    bias_s[tid] = bih[grow] + bhh[grow];
  }
  if (tid < MCB) {
    wd_s[tid] = modW[(mc0 + tid) * (H_ + 2) + H_];
    wl_s[tid] = modW[(mc0 + tid) * (H_ + 2) + H_ + 1];
    mb_s[tid] = modb[mc0 + tid];
  }
  __syncthreads();
  const bool islead = (lead_s != 0);
  int* goA  = &flags[1024 + xg_s * 16];   // top-of-step go flag (per XCD)
  int* invB = &flags[1280 + xg_s * 16];   // bar1 inv flag (per XCD)

  float creg0 = 0.f, creg1 = 0.f;     // cell state (kh==0 waves only)
  const int c = lane & 15, kg = lane >> 4;
  const int cm = c & (MCB - 1);
  const bool epi = (!kh && c < MCB);
  const int ku2 = KU >> 1;            // 8 (L0) / 16 (L1) k-tiles per wave

  // Epilogue inputs, prefetched one step ahead (read-only globals).
  float dtv[4], lqv[4], xvv[4];
  if (epi) {
#pragma unroll
    for (int r = 0; r < 4; ++r) {
      int b_ = mt * 16 + kg * 4 + r;
      dtv[r] = dseq[b_ * S_];
      lqv[r] = lqseq[b_ * S_];
      if (!layer) xvv[r] = seq[(b_ * S_) * IN_ + mc0 + c];
    }
  }

  for (int st = 0; st < S_; ++st) {
    const int e = st + 1;

    // ---- top sync: pure detect + go (NO invalidate; invB covers freshness) ----
    if (islead) {
      if (wave == 0) {
        if (st > 0) leader_detect(arrL, 2 * st, lane);
        if (lane == 0) {
          if (!layer) astore(h0done, st);          // h0 slots < st complete
          if (layer) while (aload(h0done) < e) {}  // h0 slot st at CP
          astore(goA, e);
        }
      }
    } else if (tid == 0) {
      while (aload(goA) < e) {}
    }
    __syncthreads();

    // ---- h load (one L3 exposure); lives in regs through the Whh shadow ----
    const bool havh = (st > 0);
    short8 hv[16];
    if (havh) {
      const unsigned short* hrow =
          (layer ? h1r + ((st - 1) & 1) * BH : h0r + ((st - 1) % D_) * BH) +
          (mt * 16 + c) * H_ + kh * 512;
#pragma unroll
      for (int kk = 0; kk < 16; ++kk)
        hv[kk] = *(const short8*)(hrow + kk * 32 + kg * 8);
    }
    if (layer && epi) {                 // x = h0_st (fresh via invB chain)
#pragma unroll
      for (int r = 0; r < 4; ++r) {
        int b_ = mt * 16 + kg * 4 + r;
        xvv[r] = bf2f(h0r[(st % D_) * BH + b_ * H_ + mc0 + c]);
      }
    }

    // ---- P1': mod GEMM only (2 chains), reduce m, u epilogue ----
    f32x4 mA = {0,0,0,0}, mB = {0,0,0,0};
    if (havh) {
      const unsigned short* wm = modW_s + cm * WP + kh * 512;
#pragma unroll
      for (int kk = 0; kk < 16; ++kk) {
        short8 bm = *(const short8*)(wm + kk * 32 + kg * 8);
        if (kk & 1)
          mB = __builtin_amdgcn_mfma_f32_16x16x32_bf16(hv[kk], bm, mB, 0, 0, 0);
        else
          mA = __builtin_amdgcn_mfma_f32_16x16x32_bf16(hv[kk], bm, mA, 0, 0, 0);
      }
    }
    if (kh) {
#pragma unroll
      for (int r = 0; r < 4; ++r) red_s[mt][r][lane] = mA[r] + mB[r];
    }
    __syncthreads();
    if (epi) {
      const float wd = wd_s[cm], wl = wl_s[cm], mb = mb_s[cm];
#pragma unroll
      for (int r = 0; r < 4; ++r) {
        int b_ = mt * 16 + kg * 4 + r;
        float mval = sigm(mA[r] + mB[r] + red_s[mt][r][lane] +
                          dtv[r] * wd + lqv[r] * wl + mb);
        store_short_wt(&ubuf[b_ * Kin + mc0 + c], f2bf(mval * xvv[r]));
      }
    }

    // ---- SHADOW part A: first 8 k-tiles of Whh (hides u-store drain) ----
    f32x4 p0 = {0,0,0,0}, p1 = {0,0,0,0};
    const unsigned short* w0b = Whh_s + c * WP + kh * 512;
    const unsigned short* w1b = Whh_s + (16 + c) * WP + kh * 512;
    if (havh) {
#pragma unroll
      for (int kk = 0; kk < 8; ++kk) {
        short8 w0 = *(const short8*)(w0b + kk * 32 + kg * 8);
        short8 w1 = *(const short8*)(w1b + kk * 32 + kg * 8);
        p0 = __builtin_amdgcn_mfma_f32_16x16x32_bf16(hv[kk], w0, p0, 0, 0, 0);
        p1 = __builtin_amdgcn_mfma_f32_16x16x32_bf16(hv[kk], w1, p1, 0, 0, 0);
      }
    }

    // ---- bar1 ARRIVE (u stores drained under shadow A) ----
    asm volatile("s_waitcnt vmcnt(0)" ::: "memory");
    __syncthreads();
    if (tid == 0) astore(&arrL[slice], 2 * st + 1);

    // ---- SHADOW part B: last 8 k-tiles of Whh (hides bar1 detect) ----
    if (havh) {
#pragma unroll
      for (int kk = 8; kk < 16; ++kk) {
        short8 w0 = *(const short8*)(w0b + kk * 32 + kg * 8);
        short8 w1 = *(const short8*)(w1b + kk * 32 + kg * 8);
        p0 = __builtin_amdgcn_mfma_f32_16x16x32_bf16(hv[kk], w0, p0, 0, 0, 0);
        p1 = __builtin_amdgcn_mfma_f32_16x16x32_bf16(hv[kk], w1, p1, 0, 0, 0);
      }
    }

    // ---- bar1 sync: leaders detect directly (+L0 ring back-pressure) ----
    if (islead) {
      if (wave == 0) {
        leader_detect(arrL, 2 * st + 1, lane);
        if (lane == 0) {
          if (layer) astore(l1p1done, e);          // L1 P1(st) reads complete
          if (!layer && st >= D_) {                // h0 slot reuse gate
            while (aload(l1p1done) < st - D_ + 1) {}
          }
          asm volatile("buffer_inv sc1\n\ts_waitcnt vmcnt(0)" ::: "memory");
          astore(invB, e);
        }
      }
    } else if (tid == 0) {
      while (aload(invB) < e) {}
      asm volatile("buffer_inv sc0\n\ts_waitcnt vmcnt(0)" ::: "memory");
    }
    __syncthreads();

    // ---- P2': u@Wih^T split-K; merged (p+g) reduce; cell ----
    {
      const unsigned short* urow = ubuf + (mt * 16 + c) * Kin + kh * (ku2 * 32);
      short8 uv[16];
#pragma unroll
      for (int kk = 0; kk < 16; ++kk)
        if (kk < ku2) uv[kk] = *(const short8*)(urow + kk * 32 + kg * 8);
      f32x4 g0 = {0,0,0,0}, g1 = {0,0,0,0};
      const unsigned short* v0b = Wih_s + c * WP + kh * (ku2 * 32);
      const unsigned short* v1b = Wih_s + (16 + c) * WP + kh * (ku2 * 32);
#pragma unroll
      for (int kk = 0; kk < 16; ++kk) {
        if (kk < ku2) {
          short8 v0 = *(const short8*)(v0b + kk * 32 + kg * 8);
          short8 v1 = *(const short8*)(v1b + kk * 32 + kg * 8);
          g0 = __builtin_amdgcn_mfma_f32_16x16x32_bf16(uv[kk], v0, g0, 0, 0, 0);
          g1 = __builtin_amdgcn_mfma_f32_16x16x32_bf16(uv[kk], v1, g1, 0, 0, 0);
        }
      }
      if (kh) {
#pragma unroll
        for (int r = 0; r < 4; ++r) {
          red_s[mt][r][lane] = g0[r] + p0[r];
          red_s[mt][4 + r][lane] = g1[r] + p1[r];
        }
      }
      __syncthreads();               // block-uniform branch: legal
      if (!kh) {
        const float bia0 = bias_s[c], bia1 = bias_s[16 + c];
        f32x4 s0, s1;
#pragma unroll
        for (int r = 0; r < 4; ++r) {
          g0[r] += p0[r] + red_s[mt][r][lane] + bia0;
          g1[r] += p1[r] + red_s[mt][4 + r][lane] + bia1;
        }
#pragma unroll
        for (int r = 0; r < 4; ++r) {
          s0[r] = __shfl_xor(g0[r], 8);
          s1[r] = __shfl_xor(g1[r], 8);
        }
        // Lane c<8 holds i (tile0) / g (tile1); c>=8 holds f / o.
        const bool low = c < 8;
        const int hc = hc0 + (c & 7);
        const int rbase = low ? 0 : 2;
        unsigned short* hw = layer ? h1r + (st & 1) * BH : h0r + (st % D_) * BH;
#pragma unroll
        for (int j = 0; j < 2; ++j) {
          const int rr = rbase + j;
          float iv = low ? g0[rr] : s0[rr];
          float fv = low ? s0[rr] : g0[rr];
          float gv = low ? g1[rr] : s1[rr];
          float ov = low ? s1[rr] : g1[rr];
          float cold = j ? creg1 : creg0;
          float cn = sigm(fv) * cold + sigm(iv) * tanh_(gv);
          float hn = sigm(ov) * tanh_(cn);
          if (j) creg1 = cn; else creg0 = cn;
          int b_ = mt * 16 + kg * 4 + rr;
          store_short_wt(&hw[b_ * H_ + hc], f2bf(hn));
          if (layer) {
            store_float_wt(&dout[(b_ * S_ + st) * H_ + hc], hn);
            if (st == S_ - 1) store_float_wt(&dout[B_ * S_ * H_ + b_ * H_ + hc], hn);
          }
        }
      }
    }

    // ---- bar2 ARRIVE: drain h, post arrive flag ----
    asm volatile("s_waitcnt vmcnt(0)" ::: "memory");
    __syncthreads();
    if (tid == 0) astore(&arrL[slice], 2 * st + 2);

    // ---- under-barrier prefetch: next step's read-only epilogue inputs ----
    const int t2 = st + 1;
    if (t2 < S_ && epi) {
#pragma unroll
      for (int r = 0; r < 4; ++r) {
        int b_ = mt * 16 + kg * 4 + r;
        dtv[r] = dseq[b_ * S_ + t2];
        lqv[r] = lqseq[b_ * S_ + t2];
        if (!layer) xvv[r] = seq[(b_ * S_ + t2) * IN_ + mc0 + c];
      }
    }
  }

  // ---- final: L0 leaders confirm bar2(S-1) so L1's last h0done poll ends ----
  if (!layer && islead && wave == 0) {
    leader_detect(arrL, 2 * S_, lane);
    if (lane == 0) astore(h0done, S_);
  }
}

extern "C" void kernel_launch(void* const* d_in, const int* in_sizes, int n_in,
                              void* d_out, int out_size, void* d_ws,
                              size_t ws_size, hipStream_t stream) {
  char* w = (char*)d_ws;
  int* flags = (int*)w;                                        // <8 KB used
  unsigned short* h0r = (unsigned short*)(w + 16384);          // 4 x 128 KB ring
  unsigned short* h1r = (unsigned short*)(w + 16384 + 524288); // 2 x 128 KB
  unsigned short* u0 = (unsigned short*)(w + 16384 + 524288 + 262144);          // 64 KB
  unsigned short* u1 = (unsigned short*)(w + 16384 + 524288 + 262144 + 65536);  // 128 KB

  hipMemsetAsync(flags, 0, 16384, stream);   // fresh epochs/tickets each launch

  qmog_kernel<<<NBLK, NTHR, 0, stream>>>(
      (const float*)d_in[0], (const float*)d_in[1], (const float*)d_in[2],
      (const float*)d_in[3], (const float*)d_in[4], (const float*)d_in[5],
      (const float*)d_in[6], (const float*)d_in[7], (const float*)d_in[8],
      (const float*)d_in[9], (const float*)d_in[10], (const float*)d_in[11],
      (const float*)d_in[12], (const float*)d_in[13], (const float*)d_in[14],
      (float*)d_out, flags, h0r, h1r, u0, u1);
}